// Round 2
// baseline (556.966 us; speedup 1.0000x reference)
//
#include <hip/hip_runtime.h>
#include <hip/hip_bf16.h>
#include <stdint.h>

#define NN 65536
#define NE 1048576
#define E2 (NE + NN)      // edges + self loops = 1,114,112 = 4352*256
#define HID 128
#define LP 136            // padded LDS row pitch (fp16 elems) for k_ab3/k_gnn tiles
#define RMAX 48           // max runs in LDS run-table (overflow -> global atomics)
#define TP 129            // run-table stride in words
#define TEB 256           // edges per k_edge block
#define NBE (E2/TEB)      // 4352 k_edge blocks
#define ENC_NEG 0x007FFFFFu   // encf(-inf)

typedef _Float16 h8v __attribute__((ext_vector_type(8)));
typedef __fp16 fp16x2 __attribute__((ext_vector_type(2)));
typedef __attribute__((ext_vector_type(4))) float f32x4;

__device__ __forceinline__ uint32_t pkh(float a, float b){
    union { fp16x2 h; uint32_t u; } v;
    v.h = __builtin_amdgcn_cvt_pkrtz(a, b);
    return v.u;
}
// monotone float->uint encoding for unsigned atomicMax
__device__ __forceinline__ uint32_t encf(float x){
    union { float f; uint32_t u; } v; v.f = x;
    return (v.u & 0x80000000u) ? ~v.u : (v.u | 0x80000000u);
}
__device__ __forceinline__ float decf(uint32_t u){
    union { uint32_t u; float f; } v;
    v.u = (u & 0x80000000u) ? (u ^ 0x80000000u) : ~u;
    return v.f;
}

// ---- stage one 64-elem half-row into LDS (padded LP layout) ----
__device__ __forceinline__ void stage_copy(const _Float16* g, _Float16* l){
    const uint4* gs = (const uint4*)g; uint4* ls = (uint4*)l;
    #pragma unroll
    for (int j = 0; j < 8; j++) ls[j] = gs[j];
}
__device__ __forceinline__ void stage_cvt(const float* g, _Float16* l){
    const float4* gs = (const float4*)g; uint4* ls = (uint4*)l;
    #pragma unroll
    for (int j = 0; j < 8; j++){
        float4 f0 = gs[2*j], f1 = gs[2*j+1];
        uint4 o; o.x = pkh(f0.x, f0.y); o.y = pkh(f0.z, f0.w);
        o.z = pkh(f1.x, f1.y); o.w = pkh(f1.z, f1.w);
        ls[j] = o;
    }
}

// 128x128x128 fp16 GEMM from padded LDS tiles (k_ab3 / k_gnn_ab / k_gnn)
__device__ __forceinline__ void gemm_tile(const _Float16* Ts, const _Float16* Ws,
                                          f32x4 (&acc)[2][8], int wv, int lq, int quad){
    #pragma unroll
    for (int k0 = 0; k0 < 128; k0 += 32){
        h8v af[2], bfr[8];
        #pragma unroll
        for (int rt = 0; rt < 2; rt++)
            af[rt] = *(const h8v*)(Ts + (wv*32 + rt*16 + lq)*LP + k0 + quad*8);
        #pragma unroll
        for (int ct = 0; ct < 8; ct++)
            bfr[ct] = *(const h8v*)(Ws + (ct*16 + lq)*LP + k0 + quad*8);
        #pragma unroll
        for (int rt = 0; rt < 2; rt++)
            #pragma unroll
            for (int ct = 0; ct < 8; ct++)
                acc[rt][ct] = __builtin_amdgcn_mfma_f32_16x16x32_f16(
                                  af[rt], bfr[ct], acc[rt][ct], 0, 0, 0);
    }
}

__device__ __forceinline__ void zero_acc(f32x4 (&acc)[2][8]){
    #pragma unroll
    for (int a = 0; a < 2; a++)
        #pragma unroll
        for (int b = 0; b < 8; b++)
            acc[a][b] = (f32x4){0.f, 0.f, 0.f, 0.f};
}

// ---------------- prep: weight transposes + cnt init + folded bias ----------------
struct WT { const float* s[10]; _Float16* d[10]; };
__global__ void k_prep(WT w, uint32_t* cnt,
                       const float* lb2_0, const float* gw1_0, const float* gb1_0,
                       const float* lb2_1, const float* gw1_1, const float* gb1_1,
                       float* c1p){
    int b = blockIdx.x;
    if (b < 640){
        int m = b >> 6;
        int t = (b & 63) * 256 + threadIdx.x;
        int n = t >> 7, k = t & 127;
        w.d[m][n*128 + k] = (_Float16)w.s[m][k*128 + n];
    } else if (b < 896){
        cnt[(b - 640)*256 + threadIdx.x] = 1u;        // self-loop pre-counted
    } else {
        // c1'[l][j] = gb1[j] + sum_k lb2[k]*gw1[k][j]   (folds b2 out of k_edge)
        int l = b - 896;
        int j = threadIdx.x;
        if (j < 128){
            const float* lb2 = l ? lb2_1 : lb2_0;
            const float* gw1 = l ? gw1_1 : gw1_0;
            float s = (l ? gb1_1 : gb1_0)[j];
            for (int k = 0; k < 128; k++) s += lb2[k] * gw1[k*128 + j];
            c1p[l*128 + j] = s;
        }
    }
}
__global__ void k_hist(const int* __restrict__ ei, uint32_t* cnt){
    int e = blockIdx.x * 256 + threadIdx.x;
    if (e < NE) atomicAdd(&cnt[ei[NE + e]], 1u);
}
__global__ void k_scan1(const uint32_t* __restrict__ cnt, uint32_t* __restrict__ bsum){
    __shared__ uint32_t ps[256];
    int t = threadIdx.x;
    ps[t] = cnt[blockIdx.x*256 + t]; __syncthreads();
    for (int off = 128; off > 0; off >>= 1){
        if (t < off) ps[t] += ps[t + off];
        __syncthreads();
    }
    if (t == 0) bsum[blockIdx.x] = ps[0];
}
__global__ void k_scan2(const uint32_t* __restrict__ bsum, uint32_t* __restrict__ bofs){
    __shared__ uint32_t ps[256];
    int t = threadIdx.x;
    uint32_t v = bsum[t];
    ps[t] = v; __syncthreads();
    for (int off = 1; off < 256; off <<= 1){
        uint32_t u = (t >= off) ? ps[t - off] : 0u;
        __syncthreads();
        ps[t] += u;
        __syncthreads();
    }
    bofs[t] = ps[t] - v;
}
__global__ void k_scan3(const uint32_t* __restrict__ cnt, const uint32_t* __restrict__ bofs,
                        uint32_t* __restrict__ cur){
    __shared__ uint32_t ps[256];
    int t = threadIdx.x, i = blockIdx.x*256 + t;
    uint32_t v = cnt[i];
    ps[t] = v; __syncthreads();
    for (int off = 1; off < 256; off <<= 1){
        uint32_t u = (t >= off) ? ps[t - off] : 0u;
        __syncthreads();
        ps[t] += u;
        __syncthreads();
    }
    cur[i] = bofs[blockIdx.x] + ps[t] - v;
}
__global__ void k_scatter(const int* __restrict__ ei, uint32_t* cur,
                          uint2* __restrict__ sedge){
    int e = blockIdx.x * 256 + threadIdx.x;
    if (e >= E2) return;
    uint32_t s, d;
    if (e < NE){ s = (uint32_t)ei[e]; d = (uint32_t)ei[NE + e]; }
    else { s = d = (uint32_t)(e - NE); }
    uint32_t p = atomicAdd(&cur[d], 1u);
    sedge[p] = make_uint2(s, d);
}

// ---------------- k_ab3: B0 = pos@W1b0 ; B1 = pos@W1b1 ; A0 = x@W1a0 + B0 + b1_0 ----
// pos staged once for both B GEMMs; also inits agg rows to enc(-inf).
__launch_bounds__(256, 2)
__global__ void k_ab3(const float* __restrict__ x, const float* __restrict__ pos,
                      const _Float16* __restrict__ w1aT0, const _Float16* __restrict__ w1bT0,
                      const _Float16* __restrict__ w1bT1, const float* __restrict__ lb1_0,
                      _Float16* __restrict__ Ah, _Float16* __restrict__ Bh0,
                      _Float16* __restrict__ Bh1, uint32_t* __restrict__ agg){
    __shared__ _Float16 Ts[128*LP];
    __shared__ _Float16 Ws[128*LP];
    __shared__ float b1s[128];
    const int tid = threadIdx.x;
    const int node0 = blockIdx.x * 128;
    if (tid < 128) b1s[tid] = lb1_0[tid];

    {   // init agg for this node range
        uint4* ap = (uint4*)(agg + (size_t)node0 * HID);
        uint4 v = make_uint4(ENC_NEG, ENC_NEG, ENC_NEG, ENC_NEG);
        #pragma unroll
        for (int i = 0; i < 16; i++) ap[tid + i*256] = v;
    }

    const int row = tid >> 1, half = tid & 1;
    _Float16* lT = Ts + row*LP + half*64;
    _Float16* lW = Ws + row*LP + half*64;

    stage_cvt(pos + (size_t)(node0 + row)*HID + half*64, lT);
    stage_copy(w1bT0 + row*HID + half*64, lW);
    __syncthreads();

    const int wv = tid >> 6, lane = tid & 63, lq = lane & 15, quad = lane >> 4;
    f32x4 acc0[2][8], acc1[2][8];
    zero_acc(acc0);
    gemm_tile(Ts, Ws, acc0, wv, lq, quad);     // acc0 = pos @ W1b0
    __syncthreads();

    #pragma unroll
    for (int rt = 0; rt < 2; rt++)
        #pragma unroll
        for (int ct = 0; ct < 8; ct++)
            #pragma unroll
            for (int rg = 0; rg < 4; rg++){
                int r = node0 + wv*32 + rt*16 + quad*4 + rg;
                int c = ct*16 + lq;
                Bh0[(size_t)r*HID + c] = (_Float16)acc0[rt][ct][rg];
            }
    stage_copy(w1bT1 + row*HID + half*64, lW);  // Ts (pos) kept
    __syncthreads();

    zero_acc(acc1);
    gemm_tile(Ts, Ws, acc1, wv, lq, quad);     // acc1 = pos @ W1b1
    __syncthreads();

    #pragma unroll
    for (int rt = 0; rt < 2; rt++)
        #pragma unroll
        for (int ct = 0; ct < 8; ct++)
            #pragma unroll
            for (int rg = 0; rg < 4; rg++){
                int r = node0 + wv*32 + rt*16 + quad*4 + rg;
                int c = ct*16 + lq;
                Bh1[(size_t)r*HID + c] = (_Float16)acc1[rt][ct][rg];
            }
    stage_cvt(x + (size_t)(node0 + row)*HID + half*64, lT);
    stage_copy(w1aT0 + row*HID + half*64, lW);
    __syncthreads();

    gemm_tile(Ts, Ws, acc0, wv, lq, quad);     // acc0 += x @ W1a0

    #pragma unroll
    for (int rt = 0; rt < 2; rt++)
        #pragma unroll
        for (int ct = 0; ct < 8; ct++)
            #pragma unroll
            for (int rg = 0; rg < 4; rg++){
                int r = node0 + wv*32 + rt*16 + quad*4 + rg;
                int c = ct*16 + lq;
                Ah[(size_t)r*HID + c] = (_Float16)(acc0[rt][ct][rg] + b1s[c]);
            }
}

// -------- edge kernel: agg[dst] = max over edges of relu(A[src]-B[dst]) @ W2 --------
// R2 restructure: 256-edge tiles, 512 threads, TWO barriers total (was 4 per 128).
//  - per-lane sedge loads (no LDS round-trip) -> all 16 A/B gathers issue BEFORE
//    barrier1; their latency drains at the barrier, hidden under W2 staging.
//  - run-table in its own LDS region (no Ws alias) -> tab init pre-barrier, and
//    no barrier between MFMA and flush.
//  - W2 staged once per 256 edges (halves stage traffic).
__launch_bounds__(512, 4)
__global__ void k_edge(const uint2* __restrict__ sedge,
                       const _Float16* __restrict__ Ah, const _Float16* __restrict__ Bh,
                       const _Float16* __restrict__ w2T,
                       uint32_t* __restrict__ agg){
    __shared__ _Float16 Ws[128*128];                 // 32768 B, swizzled W2
    __shared__ __align__(16) uint32_t tab[RMAX*TP];  // 24768 B run-table
    __shared__ int ds_s[TEB];
    __shared__ unsigned long long masks_s[4];
    __shared__ int run_dst_s[RMAX];
    const int tid = threadIdx.x;
    const int bid = blockIdx.x;
    const int lb  = (bid & 7) * (NBE/8) + (bid >> 3);   // XCD swizzle
    const int e0 = lb * TEB;
    const int wv = tid >> 6, lane = tid & 63, lq = lane & 15, quad = lane >> 4;
    const int r0 = wv*32 + lq, r1 = r0 + 16;

    // ---- issue all global loads up front (drain at barrier1 hides latency) ----
    const uint2 ea = sedge[e0 + r0];
    const uint2 eb = sedge[e0 + r1];

    // W2 stage: thread covers row tid>>2, 16B chunks kc = (tid&3)*4 + j
    const int srow = tid >> 2, sq = tid & 3;
    uint4 wreg[4];
    {
        const uint4* gs = (const uint4*)(w2T + srow*HID + sq*32);
        #pragma unroll
        for (int j = 0; j < 4; j++) wreg[j] = gs[j];
    }

    // boundary flags from per-lane loads (no LDS dependency)
    int d_cur = 0, d_prev = -1;
    if (tid < TEB){
        d_cur = (int)sedge[e0 + tid].y;
        if (tid > 0) d_prev = (int)sedge[e0 + tid - 1].y;
    }

    // gathers: issue now, consumed after barrier1
    const _Float16* a0p = Ah + (size_t)ea.x*HID + quad*8;
    const _Float16* a1p = Ah + (size_t)eb.x*HID + quad*8;
    const _Float16* b0p = Bh + (size_t)ea.y*HID + quad*8;
    const _Float16* b1p = Bh + (size_t)eb.y*HID + quad*8;
    h8v A0[4], A1[4], B0[4], B1[4];
    #pragma unroll
    for (int i = 0; i < 4; i++){
        A0[i] = *(const h8v*)(a0p + 32*i);
        A1[i] = *(const h8v*)(a1p + 32*i);
        B0[i] = *(const h8v*)(b0p + 32*i);
        B1[i] = *(const h8v*)(b1p + 32*i);
    }

    // ---- LDS staging (overlaps gather latency) ----
    #pragma unroll
    for (int j = 0; j < 4; j++){
        int kc = sq*4 + j;
        *(uint4*)(Ws + srow*128 + ((kc ^ (srow & 15)) << 3)) = wreg[j];
    }
    if (tid < TEB){
        ds_s[tid] = d_cur;
        bool flag = (d_cur != d_prev);
        unsigned long long m = __ballot(flag);
        if ((tid & 63) == 0) masks_s[tid >> 6] = m;
    }
    {   // init full run-table (16B vectors; RMAX*TP = 6192 words = 1548 uint4)
        uint4* t4 = (uint4*)tab;
        const uint4 vneg = make_uint4(ENC_NEG, ENC_NEG, ENC_NEG, ENC_NEG);
        for (int i = tid; i < (RMAX*TP)/4; i += 512) t4[i] = vneg;
    }
    __syncthreads();                            // barrier1: Ws/ds_s/masks/tab ready; gathers drained

    const unsigned long long m0 = masks_s[0], m1 = masks_s[1];
    const unsigned long long m2 = masks_s[2], m3 = masks_s[3];
    const int pc0 = __popcll(m0), pc1 = __popcll(m1), pc2 = __popcll(m2);
    const int nruns = pc0 + pc1 + pc2 + __popcll(m3);

    // boundary threads record their run's dst (read post-barrier2 only)
    if (tid < TEB && d_cur != d_prev){
        int seg = tid >> 6, rr = tid & 63;
        unsigned long long ms = (seg == 0) ? m0 : (seg == 1) ? m1 : (seg == 2) ? m2 : m3;
        int pref = (seg > 0 ? pc0 : 0) + (seg > 1 ? pc1 : 0) + (seg > 2 ? pc2 : 0);
        int r = pref + __popcll(ms & ((2ull << rr) - 1)) - 1;
        if (r < RMAX) run_dst_s[r] = d_cur;
    }

    // wave-uniform mask segment for this wave's 32 rows
    const int seg = wv >> 1;
    const unsigned long long mseg = (seg == 0) ? m0 : (seg == 1) ? m1 : (seg == 2) ? m2 : m3;
    const int pref = (seg > 0 ? pc0 : 0) + (seg > 1 ? pc1 : 0) + (seg > 2 ? pc2 : 0);

    f32x4 acc[2][8];
    zero_acc(acc);

    const h8v zero8 = (h8v)(_Float16)0;
    #pragma unroll
    for (int i = 0; i < 4; i++){
        h8v a0 = __builtin_elementwise_max(A0[i] - B0[i], zero8);
        h8v a1 = __builtin_elementwise_max(A1[i] - B1[i], zero8);
        const int kcb = i*4;
        #pragma unroll
        for (int ct = 0; ct < 8; ct++){
            h8v b = *(const h8v*)(Ws + (ct*16 + lq)*128 + (((kcb + quad) ^ lq) << 3));
            acc[0][ct] = __builtin_amdgcn_mfma_f32_16x16x32_f16(a0, b, acc[0][ct], 0, 0, 0);
            acc[1][ct] = __builtin_amdgcn_mfma_f32_16x16x32_f16(a1, b, acc[1][ct], 0, 0, 0);
        }
    }

    // flush acc -> run-table (tab does not alias Ws: no barrier needed)
    #pragma unroll
    for (int rt = 0; rt < 2; rt++){
        const int rb = wv*32 + rt*16 + quad*4;
        int rid[4];
        #pragma unroll
        for (int i = 0; i < 4; i++){
            int rr = (rb + i) & 63;
            rid[i] = pref + __popcll(mseg & ((2ull << rr) - 1)) - 1;
        }
        const bool b01 = rid[1] != rid[0];
        const bool b12 = rid[2] != rid[1];
        const bool b23 = rid[3] != rid[2];
        #pragma unroll
        for (int ct = 0; ct < 8; ct++){
            const int c = ct*16 + lq;
            float v0 = acc[rt][ct][0], v1 = acc[rt][ct][1];
            float v2 = acc[rt][ct][2], v3 = acc[rt][ct][3];
            #define FLUSH(ID, R, V) do{ uint32_t ev = encf(V); \
                if (__builtin_expect((ID) < RMAX, 1)) atomicMax(&tab[(ID)*TP + c], ev); \
                else atomicMax(&agg[(size_t)ds_s[R]*HID + c], ev); }while(0)
            if (b01) FLUSH(rid[0], rb+0, v0); else v1 = fmaxf(v1, v0);
            if (b12) FLUSH(rid[1], rb+1, v1); else v2 = fmaxf(v2, v1);
            if (b23) FLUSH(rid[2], rb+2, v2); else v3 = fmaxf(v3, v2);
            FLUSH(rid[3], rb+3, v3);
            #undef FLUSH
        }
    }
    __syncthreads();                            // barrier2: table + run_dst complete

    {   // flush: boundary runs -> atomicMax; interior runs sole-writer -> plain store
        const int c = tid & 127;
        const int ntab = nruns < RMAX ? nruns : RMAX;
        for (int r = tid >> 7; r < ntab; r += 4){
            uint32_t v = tab[r*TP + c];
            uint32_t* dst = &agg[(size_t)run_dst_s[r]*HID + c];
            if (r == 0 || r == nruns-1 || nruns > RMAX) atomicMax(dst, v);
            else *dst = v;
        }
    }
}

// -------- fused layer-0 global nn + layer-1 A: out0 = relu((agg)@G1 + c1')@G2 + c2 ;
//          A1 = out0@W1a1 + B1 + b1_1 ; re-inits agg rows for layer 1 --------
__launch_bounds__(256, 2)
__global__ void k_gnn_ab(uint32_t* __restrict__ agg,
                         const _Float16* __restrict__ g1T, const _Float16* __restrict__ g2T,
                         const float* __restrict__ c1p, const float* __restrict__ gb2,
                         const _Float16* __restrict__ w1aT1, const _Float16* __restrict__ Bh1,
                         const float* __restrict__ lb1_1,
                         _Float16* __restrict__ Ah){
    __shared__ _Float16 Ts[128*LP];
    __shared__ _Float16 Ws[128*LP];
    __shared__ float c1s[128];
    __shared__ float c2s[128];
    __shared__ float b1s[128];
    const int tid = threadIdx.x;
    const int node0 = blockIdx.x * 128;
    if (tid < 128){ c1s[tid] = c1p[tid]; c2s[tid] = gb2[tid]; b1s[tid] = lb1_1[tid]; }
    const int row = tid >> 1, half = tid & 1;
    _Float16* lW = Ws + row*LP + half*64;

    {   // decode agg tile (+re-init to enc(-inf)) and stage G1^T
        uint4* ga = (uint4*)(agg + (size_t)(node0 + row)*HID + half*64);
        _Float16* lt = Ts + row*LP + half*64;
        const uint4 vneg = make_uint4(ENC_NEG, ENC_NEG, ENC_NEG, ENC_NEG);
        #pragma unroll
        for (int j = 0; j < 16; j++){
            uint4 u = ga[j];
            ga[j] = vneg;
            uint2 o; o.x = pkh(decf(u.x), decf(u.y)); o.y = pkh(decf(u.z), decf(u.w));
            *(uint2*)(lt + j*4) = o;
        }
        stage_copy(g1T + row*HID + half*64, lW);
    }
    __syncthreads();

    const int wv = tid >> 6, lane = tid & 63, lq = lane & 15, quad = lane >> 4;
    f32x4 acc[2][8];
    zero_acc(acc);
    gemm_tile(Ts, Ws, acc, wv, lq, quad);       // agg @ G1
    __syncthreads();

    #pragma unroll
    for (int rt = 0; rt < 2; rt++)
        #pragma unroll
        for (int ct = 0; ct < 8; ct++)
            #pragma unroll
            for (int rg = 0; rg < 4; rg++){
                int rr = wv*32 + rt*16 + quad*4 + rg;
                int c  = ct*16 + lq;
                Ts[rr*LP + c] = (_Float16)fmaxf(acc[rt][ct][rg] + c1s[c], 0.f);
            }
    stage_copy(g2T + row*HID + half*64, lW);
    __syncthreads();

    zero_acc(acc);
    gemm_tile(Ts, Ws, acc, wv, lq, quad);       // P @ G2
    __syncthreads();

    #pragma unroll
    for (int rt = 0; rt < 2; rt++)              // out0 -> Ts (fp16), stage W1a1^T
        #pragma unroll
        for (int ct = 0; ct < 8; ct++)
            #pragma unroll
            for (int rg = 0; rg < 4; rg++){
                int rr = wv*32 + rt*16 + quad*4 + rg;
                int c  = ct*16 + lq;
                Ts[rr*LP + c] = (_Float16)(acc[rt][ct][rg] + c2s[c]);
            }
    stage_copy(w1aT1 + row*HID + half*64, lW);
    __syncthreads();

    zero_acc(acc);
    gemm_tile(Ts, Ws, acc, wv, lq, quad);       // out0 @ W1a1
    __syncthreads();

    stage_copy(Bh1 + (size_t)(node0 + row)*HID + half*64, Ts + row*LP + half*64);
    __syncthreads();

    #pragma unroll
    for (int rt = 0; rt < 2; rt++)
        #pragma unroll
        for (int ct = 0; ct < 8; ct++)
            #pragma unroll
            for (int rg = 0; rg < 4; rg++){
                int rr = wv*32 + rt*16 + quad*4 + rg;
                int c  = ct*16 + lq;
                float v = acc[rt][ct][rg] + (float)Ts[rr*LP + c] + b1s[c];
                Ah[(size_t)(node0 + rr)*HID + c] = (_Float16)v;
            }
}

// -------- final global nn: out = relu(agg@G1 + c1') @ G2 + c2 --------
__launch_bounds__(256, 2)
__global__ void k_gnn(const uint32_t* __restrict__ agg,
                      const _Float16* __restrict__ g1T, const _Float16* __restrict__ g2T,
                      const float* __restrict__ c1p, const float* __restrict__ gb2,
                      float* __restrict__ outf){
    __shared__ _Float16 Ts[128*LP];
    __shared__ _Float16 Ws[128*LP];
    __shared__ float c1s[128];
    __shared__ float c2s[128];
    const int tid = threadIdx.x;
    const int node0 = blockIdx.x * 128;
    if (tid < 128){ c1s[tid] = c1p[tid]; c2s[tid] = gb2[tid]; }
    const int row = tid >> 1, half = tid & 1;
    _Float16* lW = Ws + row*LP + half*64;

    {   // decode agg tile + stage G1^T
        const uint4* ga = (const uint4*)(agg + (size_t)(node0 + row)*HID + half*64);
        _Float16* lt = Ts + row*LP + half*64;
        #pragma unroll
        for (int j = 0; j < 16; j++){
            uint4 u = ga[j];
            uint2 o; o.x = pkh(decf(u.x), decf(u.y)); o.y = pkh(decf(u.z), decf(u.w));
            *(uint2*)(lt + j*4) = o;
        }
        stage_copy(g1T + row*HID + half*64, lW);
    }
    __syncthreads();

    const int wv = tid >> 6, lane = tid & 63, lq = lane & 15, quad = lane >> 4;
    f32x4 acc[2][8];
    zero_acc(acc);
    gemm_tile(Ts, Ws, acc, wv, lq, quad);
    __syncthreads();

    #pragma unroll
    for (int rt = 0; rt < 2; rt++)
        #pragma unroll
        for (int ct = 0; ct < 8; ct++)
            #pragma unroll
            for (int rg = 0; rg < 4; rg++){
                int rr = wv*32 + rt*16 + quad*4 + rg;
                int c  = ct*16 + lq;
                Ts[rr*LP + c] = (_Float16)fmaxf(acc[rt][ct][rg] + c1s[c], 0.f);
            }
    stage_copy(g2T + row*HID + half*64, lW);
    __syncthreads();

    zero_acc(acc);
    gemm_tile(Ts, Ws, acc, wv, lq, quad);

    #pragma unroll
    for (int rt = 0; rt < 2; rt++)
        #pragma unroll
        for (int ct = 0; ct < 8; ct++)
            #pragma unroll
            for (int rg = 0; rg < 4; rg++){
                int r = node0 + wv*32 + rt*16 + quad*4 + rg;
                int c = ct*16 + lq;
                outf[(size_t)r*HID + c] = acc[rt][ct][rg] + c2s[c];
            }
}

extern "C" void kernel_launch(void* const* d_in, const int* in_sizes, int n_in,
                              void* d_out, int out_size, void* d_ws, size_t ws_size,
                              hipStream_t stream){
    const float* x   = (const float*)d_in[0];
    const float* pos = (const float*)d_in[1];
    const int*   ei  = (const int*)d_in[2];
    const float* W[16];
    for (int i = 0; i < 16; i++) W[i] = (const float*)d_in[3 + i];
    // per layer l: lw1=W[8l+0] lb1=+1 lw2=+2 lb2=+3 gw1=+4 gb1=+5 gw2=+6 gb2=+7

    uint8_t* p = (uint8_t*)d_ws;
    _Float16* wT[10];
    for (int i = 0; i < 10; i++) wT[i] = (_Float16*)(p + (size_t)i * 32768);
    size_t off = 10 * 32768;
    _Float16* Ah  = (_Float16*)(p + off); off += (size_t)NN * HID * 2;
    _Float16* Bh0 = (_Float16*)(p + off); off += (size_t)NN * HID * 2;
    _Float16* Bh1 = (_Float16*)(p + off); off += (size_t)NN * HID * 2;
    uint32_t* agg = (uint32_t*)(p + off); off += (size_t)NN * HID * 4;
    uint32_t* cnt = (uint32_t*)(p + off); off += (size_t)NN * 4;
    uint32_t* cur = (uint32_t*)(p + off); off += (size_t)NN * 4;
    uint32_t* bsum = (uint32_t*)(p + off); off += 256 * 4;
    uint32_t* bofs = (uint32_t*)(p + off); off += 256 * 4;
    float* c1p = (float*)(p + off); off += 256 * 4;
    uint2* sedge = (uint2*)(p + off); off += (size_t)E2 * 8;
    (void)ws_size; (void)in_sizes; (void)n_in; (void)out_size;

    // weight transpose slots per layer: W1a^T, W1b^T, W2^T, G1^T, G2^T
    WT wt;
    for (int l = 0; l < 2; l++){
        wt.s[5*l + 0] = W[8*l + 0];
        wt.s[5*l + 1] = W[8*l + 0] + 128*128;
        wt.s[5*l + 2] = W[8*l + 2];
        wt.s[5*l + 3] = W[8*l + 4];
        wt.s[5*l + 4] = W[8*l + 6];
        for (int j = 0; j < 5; j++) wt.d[5*l + j] = wT[5*l + j];
    }
    k_prep<<<898, 256, 0, stream>>>(wt, cnt, W[3], W[4], W[5], W[11], W[12], W[13], c1p);

    // dst-sorted edge list (shared by both layers)
    k_hist<<<NE/256, 256, 0, stream>>>(ei, cnt);
    k_scan1<<<256, 256, 0, stream>>>(cnt, bsum);
    k_scan2<<<1, 256, 0, stream>>>(bsum, bofs);
    k_scan3<<<256, 256, 0, stream>>>(cnt, bofs, cur);
    k_scatter<<<(E2 + 255)/256, 256, 0, stream>>>(ei, cur, sedge);

    k_ab3<<<NN/128, 256, 0, stream>>>(x, pos, wT[0], wT[1], wT[6], W[1],
                                      Ah, Bh0, Bh1, agg);
    k_edge<<<NBE, 512, 0, stream>>>(sedge, Ah, Bh0, wT[2], agg);
    k_gnn_ab<<<NN/128, 256, 0, stream>>>(agg, wT[3], wT[4], c1p, W[7],
                                         wT[5], Bh1, W[9], Ah);
    k_edge<<<NBE, 512, 0, stream>>>(sedge, Ah, Bh1, wT[7], agg);
    k_gnn<<<NN/128, 256, 0, stream>>>(agg, wT[8], wT[9], c1p + 128, W[15],
                                      (float*)d_out);
}

// Round 3
// 539.204 us; speedup vs baseline: 1.0329x; 1.0329x over previous
//
#include <hip/hip_runtime.h>
#include <hip/hip_bf16.h>
#include <stdint.h>

#define NN 65536
#define NE 1048576
#define E2 (NE + NN)      // edges + self loops = 1,114,112 = 8704*128
#define HID 128
#define LP 136            // padded LDS row pitch (fp16 elems) for k_ab3/k_gnn tiles
#define RMAX 20           // max runs in LDS run-table (overflow -> global atomics)
#define TP 129            // run-table stride in words
#define ENC_NEG 0x007FFFFFu   // encf(-inf)

typedef _Float16 h8v __attribute__((ext_vector_type(8)));
typedef __fp16 fp16x2 __attribute__((ext_vector_type(2)));
typedef __attribute__((ext_vector_type(4))) float f32x4;

__device__ __forceinline__ uint32_t pkh(float a, float b){
    union { fp16x2 h; uint32_t u; } v;
    v.h = __builtin_amdgcn_cvt_pkrtz(a, b);
    return v.u;
}
// monotone float->uint encoding for unsigned atomicMax (branchless)
__device__ __forceinline__ uint32_t encf(float x){
    union { float f; uint32_t u; } v; v.f = x;
    return v.u ^ (uint32_t)(((int32_t)v.u >> 31) | 0x80000000);
}
__device__ __forceinline__ float decf(uint32_t u){
    union { uint32_t u; float f; } v;
    v.u = u ^ (uint32_t)(~((int32_t)u >> 31) | 0x80000000);
    return v.f;
}

// ---- stage one 64-elem half-row into LDS (padded LP layout) ----
__device__ __forceinline__ void stage_copy(const _Float16* g, _Float16* l){
    const uint4* gs = (const uint4*)g; uint4* ls = (uint4*)l;
    #pragma unroll
    for (int j = 0; j < 8; j++) ls[j] = gs[j];
}
__device__ __forceinline__ void stage_cvt(const float* g, _Float16* l){
    const float4* gs = (const float4*)g; uint4* ls = (uint4*)l;
    #pragma unroll
    for (int j = 0; j < 8; j++){
        float4 f0 = gs[2*j], f1 = gs[2*j+1];
        uint4 o; o.x = pkh(f0.x, f0.y); o.y = pkh(f0.z, f0.w);
        o.z = pkh(f1.x, f1.y); o.w = pkh(f1.z, f1.w);
        ls[j] = o;
    }
}

// 128x128x128 fp16 GEMM from padded LDS tiles (k_ab3 / k_gnn_ab / k_gnn)
__device__ __forceinline__ void gemm_tile(const _Float16* Ts, const _Float16* Ws,
                                          f32x4 (&acc)[2][8], int wv, int lq, int quad){
    #pragma unroll
    for (int k0 = 0; k0 < 128; k0 += 32){
        h8v af[2], bfr[8];
        #pragma unroll
        for (int rt = 0; rt < 2; rt++)
            af[rt] = *(const h8v*)(Ts + (wv*32 + rt*16 + lq)*LP + k0 + quad*8);
        #pragma unroll
        for (int ct = 0; ct < 8; ct++)
            bfr[ct] = *(const h8v*)(Ws + (ct*16 + lq)*LP + k0 + quad*8);
        #pragma unroll
        for (int rt = 0; rt < 2; rt++)
            #pragma unroll
            for (int ct = 0; ct < 8; ct++)
                acc[rt][ct] = __builtin_amdgcn_mfma_f32_16x16x32_f16(
                                  af[rt], bfr[ct], acc[rt][ct], 0, 0, 0);
    }
}

__device__ __forceinline__ void zero_acc(f32x4 (&acc)[2][8]){
    #pragma unroll
    for (int a = 0; a < 2; a++)
        #pragma unroll
        for (int b = 0; b < 8; b++)
            acc[a][b] = (f32x4){0.f, 0.f, 0.f, 0.f};
}

// ---------------- prep: weight transposes + cnt init + folded bias ----------------
struct WT { const float* s[10]; _Float16* d[10]; };
__global__ void k_prep(WT w, uint32_t* cnt,
                       const float* lb2_0, const float* gw1_0, const float* gb1_0,
                       const float* lb2_1, const float* gw1_1, const float* gb1_1,
                       float* c1p){
    int b = blockIdx.x;
    if (b < 640){
        int m = b >> 6;
        int t = (b & 63) * 256 + threadIdx.x;
        int n = t >> 7, k = t & 127;
        w.d[m][n*128 + k] = (_Float16)w.s[m][k*128 + n];
    } else if (b < 896){
        cnt[(b - 640)*256 + threadIdx.x] = 1u;        // self-loop pre-counted
    } else {
        // c1'[l][j] = gb1[j] + sum_k lb2[k]*gw1[k][j]   (folds b2 out of k_edge)
        int l = b - 896;
        int j = threadIdx.x;
        if (j < 128){
            const float* lb2 = l ? lb2_1 : lb2_0;
            const float* gw1 = l ? gw1_1 : gw1_0;
            float s = (l ? gb1_1 : gb1_0)[j];
            for (int k = 0; k < 128; k++) s += lb2[k] * gw1[k*128 + j];
            c1p[l*128 + j] = s;
        }
    }
}
__global__ void k_hist(const int* __restrict__ ei, uint32_t* cnt){
    int e = blockIdx.x * 256 + threadIdx.x;
    if (e < NE) atomicAdd(&cnt[ei[NE + e]], 1u);
}
__global__ void k_scan1(const uint32_t* __restrict__ cnt, uint32_t* __restrict__ bsum){
    __shared__ uint32_t ps[256];
    int t = threadIdx.x;
    ps[t] = cnt[blockIdx.x*256 + t]; __syncthreads();
    for (int off = 128; off > 0; off >>= 1){
        if (t < off) ps[t] += ps[t + off];
        __syncthreads();
    }
    if (t == 0) bsum[blockIdx.x] = ps[0];
}
__global__ void k_scan2(const uint32_t* __restrict__ bsum, uint32_t* __restrict__ bofs){
    __shared__ uint32_t ps[256];
    int t = threadIdx.x;
    uint32_t v = bsum[t];
    ps[t] = v; __syncthreads();
    for (int off = 1; off < 256; off <<= 1){
        uint32_t u = (t >= off) ? ps[t - off] : 0u;
        __syncthreads();
        ps[t] += u;
        __syncthreads();
    }
    bofs[t] = ps[t] - v;
}
__global__ void k_scan3(const uint32_t* __restrict__ cnt, const uint32_t* __restrict__ bofs,
                        uint32_t* __restrict__ cur){
    __shared__ uint32_t ps[256];
    int t = threadIdx.x, i = blockIdx.x*256 + t;
    uint32_t v = cnt[i];
    ps[t] = v; __syncthreads();
    for (int off = 1; off < 256; off <<= 1){
        uint32_t u = (t >= off) ? ps[t - off] : 0u;
        __syncthreads();
        ps[t] += u;
        __syncthreads();
    }
    cur[i] = bofs[blockIdx.x] + ps[t] - v;
}
__global__ void k_scatter(const int* __restrict__ ei, uint32_t* cur,
                          uint2* __restrict__ sedge){
    int e = blockIdx.x * 256 + threadIdx.x;
    if (e >= E2) return;
    uint32_t s, d;
    if (e < NE){ s = (uint32_t)ei[e]; d = (uint32_t)ei[NE + e]; }
    else { s = d = (uint32_t)(e - NE); }
    uint32_t p = atomicAdd(&cur[d], 1u);
    sedge[p] = make_uint2(s, d);
}

// ---------------- k_ab3: B0 = pos@W1b0 ; B1 = pos@W1b1 ; A0 = x@W1a0 + B0 + b1_0 ----
// pos staged once for both B GEMMs; also inits agg rows to enc(-inf).
__launch_bounds__(256, 2)
__global__ void k_ab3(const float* __restrict__ x, const float* __restrict__ pos,
                      const _Float16* __restrict__ w1aT0, const _Float16* __restrict__ w1bT0,
                      const _Float16* __restrict__ w1bT1, const float* __restrict__ lb1_0,
                      _Float16* __restrict__ Ah, _Float16* __restrict__ Bh0,
                      _Float16* __restrict__ Bh1, uint32_t* __restrict__ agg){
    __shared__ _Float16 Ts[128*LP];
    __shared__ _Float16 Ws[128*LP];
    __shared__ float b1s[128];
    const int tid = threadIdx.x;
    const int node0 = blockIdx.x * 128;
    if (tid < 128) b1s[tid] = lb1_0[tid];

    {   // init agg for this node range
        uint4* ap = (uint4*)(agg + (size_t)node0 * HID);
        uint4 v = make_uint4(ENC_NEG, ENC_NEG, ENC_NEG, ENC_NEG);
        #pragma unroll
        for (int i = 0; i < 16; i++) ap[tid + i*256] = v;
    }

    const int row = tid >> 1, half = tid & 1;
    _Float16* lT = Ts + row*LP + half*64;
    _Float16* lW = Ws + row*LP + half*64;

    stage_cvt(pos + (size_t)(node0 + row)*HID + half*64, lT);
    stage_copy(w1bT0 + row*HID + half*64, lW);
    __syncthreads();

    const int wv = tid >> 6, lane = tid & 63, lq = lane & 15, quad = lane >> 4;
    f32x4 acc0[2][8], acc1[2][8];
    zero_acc(acc0);
    gemm_tile(Ts, Ws, acc0, wv, lq, quad);     // acc0 = pos @ W1b0
    __syncthreads();

    #pragma unroll
    for (int rt = 0; rt < 2; rt++)
        #pragma unroll
        for (int ct = 0; ct < 8; ct++)
            #pragma unroll
            for (int rg = 0; rg < 4; rg++){
                int r = node0 + wv*32 + rt*16 + quad*4 + rg;
                int c = ct*16 + lq;
                Bh0[(size_t)r*HID + c] = (_Float16)acc0[rt][ct][rg];
            }
    stage_copy(w1bT1 + row*HID + half*64, lW);  // Ts (pos) kept
    __syncthreads();

    zero_acc(acc1);
    gemm_tile(Ts, Ws, acc1, wv, lq, quad);     // acc1 = pos @ W1b1
    __syncthreads();

    #pragma unroll
    for (int rt = 0; rt < 2; rt++)
        #pragma unroll
        for (int ct = 0; ct < 8; ct++)
            #pragma unroll
            for (int rg = 0; rg < 4; rg++){
                int r = node0 + wv*32 + rt*16 + quad*4 + rg;
                int c = ct*16 + lq;
                Bh1[(size_t)r*HID + c] = (_Float16)acc1[rt][ct][rg];
            }
    stage_cvt(x + (size_t)(node0 + row)*HID + half*64, lT);
    stage_copy(w1aT0 + row*HID + half*64, lW);
    __syncthreads();

    gemm_tile(Ts, Ws, acc0, wv, lq, quad);     // acc0 += x @ W1a0

    #pragma unroll
    for (int rt = 0; rt < 2; rt++)
        #pragma unroll
        for (int ct = 0; ct < 8; ct++)
            #pragma unroll
            for (int rg = 0; rg < 4; rg++){
                int r = node0 + wv*32 + rt*16 + quad*4 + rg;
                int c = ct*16 + lq;
                Ah[(size_t)r*HID + c] = (_Float16)(acc0[rt][ct][rg] + b1s[c]);
            }
}

// -------- edge kernel: agg[dst] = max over edges of relu(A[src]-B[dst]) @ W2 --------
// R3: R1 geometry (128 edges / 256 threads) with 2 barriers instead of 4:
//  - run-table in its OWN LDS region (RMAX 48->20): tab init moves pre-barrier1,
//    no barrier between MFMA and tab flush.
//  - per-lane sedge loads (no ss_s round-trip): all 16 A/B gathers issue BEFORE
//    barrier1 and drain under W2 staging + tab init.
//  - __launch_bounds__(256,3): reg cap 170 (3 waves/SIMD, 12 waves/CU) -- R2's
//    regression was forced spills at the 128-reg cap (WRITE_SIZE 37->130 MB).
__launch_bounds__(256, 3)
__global__ void k_edge(const uint2* __restrict__ sedge,
                       const _Float16* __restrict__ Ah, const _Float16* __restrict__ Bh,
                       const _Float16* __restrict__ w2T,
                       uint32_t* __restrict__ agg){
    __shared__ _Float16 Ws[128*128];                 // 32768 B, swizzled W2
    __shared__ __align__(16) uint32_t tab[RMAX*TP];  // 10320 B run-table (own region)
    __shared__ int ds_s[128];
    __shared__ unsigned long long masks_s[2];
    __shared__ int run_dst_s[RMAX];
    const int tid = threadIdx.x;
    const int bid = blockIdx.x;
    const int lb  = (bid & 7) * (E2/128/8) + (bid >> 3);   // XCD swizzle
    const int e0 = lb * 128;
    const int wv = tid >> 6, lane = tid & 63, lq = lane & 15, quad = lane >> 4;
    const int r0 = wv*32 + lq, r1 = r0 + 16;
    const int row = tid >> 1, half = tid & 1;

    // ---- per-lane edge loads (no LDS round-trip for gather addresses) ----
    const uint2 ea = sedge[e0 + r0];
    const uint2 eb = sedge[e0 + r1];
    int d_cur = 0, d_prev = -1;
    if (tid < 128){
        d_cur = (int)sedge[e0 + tid].y;
        if (tid > 0) d_prev = (int)sedge[e0 + tid - 1].y;
    }

    // W2 stage loads (independent of ea/eb; in flight during their wait)
    const uint4* gs = (const uint4*)(w2T + row*HID + half*64);

    // gathers: issue ASAP; they drain during LDS staging + barrier1
    const _Float16* a0p = Ah + (size_t)ea.x*HID + quad*8;
    const _Float16* a1p = Ah + (size_t)eb.x*HID + quad*8;
    const _Float16* b0p = Bh + (size_t)ea.y*HID + quad*8;
    const _Float16* b1p = Bh + (size_t)eb.y*HID + quad*8;
    h8v A0[4], A1[4], B0[4], B1[4];
    #pragma unroll
    for (int i = 0; i < 4; i++){
        A0[i] = *(const h8v*)(a0p + 32*i);
        A1[i] = *(const h8v*)(a1p + 32*i);
        B0[i] = *(const h8v*)(b0p + 32*i);
        B1[i] = *(const h8v*)(b1p + 32*i);
    }

    // ---- LDS staging (overlaps gather latency) ----
    #pragma unroll
    for (int j = 0; j < 8; j++){   // swizzled: 16B chunk kc of row r -> slot kc ^ (r&15)
        int kc = half*8 + j;
        *(uint4*)(Ws + row*128 + ((kc ^ (row & 15)) << 3)) = gs[j];
    }
    if (tid < 128){
        ds_s[tid] = d_cur;
        bool flag = (d_cur != d_prev);
        unsigned long long m = __ballot(flag);
        if ((tid & 63) == 0) masks_s[tid >> 6] = m;
    }
    {   // init run-table (RMAX*TP = 2580 words = 645 uint4, exact)
        uint4* t4 = (uint4*)tab;
        const uint4 vneg = make_uint4(ENC_NEG, ENC_NEG, ENC_NEG, ENC_NEG);
        for (int i = tid; i < (RMAX*TP)/4; i += 256) t4[i] = vneg;
    }
    __syncthreads();                            // barrier1: Ws/ds_s/masks/tab ready

    const unsigned long long m0 = masks_s[0], m1 = masks_s[1];
    const int c0 = __popcll(m0);
    const int nruns = c0 + __popcll(m1);

    // boundary threads record their run's dst (read post-barrier2 only)
    if (tid < 128 && d_cur != d_prev){
        int r;
        if (tid < 64) r = __popcll(m0 & ((2ull << tid) - 1)) - 1;
        else          r = c0 + __popcll(m1 & ((2ull << (tid-64)) - 1)) - 1;
        if (r < RMAX) run_dst_s[r] = d_cur;
    }

    f32x4 acc[2][8];
    zero_acc(acc);

    const h8v zero8 = (h8v)(_Float16)0;
    #pragma unroll
    for (int i = 0; i < 4; i++){
        h8v a0 = __builtin_elementwise_max(A0[i] - B0[i], zero8);
        h8v a1 = __builtin_elementwise_max(A1[i] - B1[i], zero8);
        const int kcb = i*4;
        #pragma unroll
        for (int ct = 0; ct < 8; ct++){
            h8v b = *(const h8v*)(Ws + (ct*16 + lq)*128 + (((kcb + quad) ^ lq) << 3));
            acc[0][ct] = __builtin_amdgcn_mfma_f32_16x16x32_f16(a0, b, acc[0][ct], 0, 0, 0);
            acc[1][ct] = __builtin_amdgcn_mfma_f32_16x16x32_f16(a1, b, acc[1][ct], 0, 0, 0);
        }
    }

    // flush acc -> run-table (tab does not alias Ws: no barrier needed)
    #pragma unroll
    for (int rt = 0; rt < 2; rt++){
        const int rb = wv*32 + rt*16 + quad*4;
        int rid[4];
        #pragma unroll
        for (int i = 0; i < 4; i++){
            int r = rb + i;
            if (r < 64) rid[i] = __popcll(m0 & ((2ull << r) - 1)) - 1;
            else        rid[i] = c0 + __popcll(m1 & ((2ull << (r-64)) - 1)) - 1;
        }
        const bool b01 = rid[1] != rid[0];
        const bool b12 = rid[2] != rid[1];
        const bool b23 = rid[3] != rid[2];
        #pragma unroll
        for (int ct = 0; ct < 8; ct++){
            const int c = ct*16 + lq;
            float v0 = acc[rt][ct][0], v1 = acc[rt][ct][1];
            float v2 = acc[rt][ct][2], v3 = acc[rt][ct][3];
            #define FLUSH(ID, R, V) do{ uint32_t ev = encf(V); \
                if (__builtin_expect((ID) < RMAX, 1)) atomicMax(&tab[(ID)*TP + c], ev); \
                else atomicMax(&agg[(size_t)ds_s[R]*HID + c], ev); }while(0)
            if (b01) FLUSH(rid[0], rb+0, v0); else v1 = fmaxf(v1, v0);
            if (b12) FLUSH(rid[1], rb+1, v1); else v2 = fmaxf(v2, v1);
            if (b23) FLUSH(rid[2], rb+2, v2); else v3 = fmaxf(v3, v2);
            FLUSH(rid[3], rb+3, v3);
            #undef FLUSH
        }
    }
    __syncthreads();                            // barrier2: table + run_dst complete

    {   // flush: boundary runs -> atomicMax; interior runs sole-writer -> plain store
        const int c = tid & 127;
        const int ntab = nruns < RMAX ? nruns : RMAX;
        for (int r = tid >> 7; r < ntab; r += 2){
            uint32_t v = tab[r*TP + c];
            uint32_t* dst = &agg[(size_t)run_dst_s[r]*HID + c];
            if (r == 0 || r == nruns-1 || nruns > RMAX) atomicMax(dst, v);
            else *dst = v;
        }
    }
}

// -------- fused layer-0 global nn + layer-1 A: out0 = relu((agg)@G1 + c1')@G2 + c2 ;
//          A1 = out0@W1a1 + B1 + b1_1 ; re-inits agg rows for layer 1 --------
__launch_bounds__(256, 2)
__global__ void k_gnn_ab(uint32_t* __restrict__ agg,
                         const _Float16* __restrict__ g1T, const _Float16* __restrict__ g2T,
                         const float* __restrict__ c1p, const float* __restrict__ gb2,
                         const _Float16* __restrict__ w1aT1, const _Float16* __restrict__ Bh1,
                         const float* __restrict__ lb1_1,
                         _Float16* __restrict__ Ah){
    __shared__ _Float16 Ts[128*LP];
    __shared__ _Float16 Ws[128*LP];
    __shared__ float c1s[128];
    __shared__ float c2s[128];
    __shared__ float b1s[128];
    const int tid = threadIdx.x;
    const int node0 = blockIdx.x * 128;
    if (tid < 128){ c1s[tid] = c1p[tid]; c2s[tid] = gb2[tid]; b1s[tid] = lb1_1[tid]; }
    const int row = tid >> 1, half = tid & 1;
    _Float16* lW = Ws + row*LP + half*64;

    {   // decode agg tile (+re-init to enc(-inf)) and stage G1^T
        uint4* ga = (uint4*)(agg + (size_t)(node0 + row)*HID + half*64);
        _Float16* lt = Ts + row*LP + half*64;
        const uint4 vneg = make_uint4(ENC_NEG, ENC_NEG, ENC_NEG, ENC_NEG);
        #pragma unroll
        for (int j = 0; j < 16; j++){
            uint4 u = ga[j];
            ga[j] = vneg;
            uint2 o; o.x = pkh(decf(u.x), decf(u.y)); o.y = pkh(decf(u.z), decf(u.w));
            *(uint2*)(lt + j*4) = o;
        }
        stage_copy(g1T + row*HID + half*64, lW);
    }
    __syncthreads();

    const int wv = tid >> 6, lane = tid & 63, lq = lane & 15, quad = lane >> 4;
    f32x4 acc[2][8];
    zero_acc(acc);
    gemm_tile(Ts, Ws, acc, wv, lq, quad);       // agg @ G1
    __syncthreads();

    #pragma unroll
    for (int rt = 0; rt < 2; rt++)
        #pragma unroll
        for (int ct = 0; ct < 8; ct++)
            #pragma unroll
            for (int rg = 0; rg < 4; rg++){
                int rr = wv*32 + rt*16 + quad*4 + rg;
                int c  = ct*16 + lq;
                Ts[rr*LP + c] = (_Float16)fmaxf(acc[rt][ct][rg] + c1s[c], 0.f);
            }
    stage_copy(g2T + row*HID + half*64, lW);
    __syncthreads();

    zero_acc(acc);
    gemm_tile(Ts, Ws, acc, wv, lq, quad);       // P @ G2
    __syncthreads();

    #pragma unroll
    for (int rt = 0; rt < 2; rt++)              // out0 -> Ts (fp16), stage W1a1^T
        #pragma unroll
        for (int ct = 0; ct < 8; ct++)
            #pragma unroll
            for (int rg = 0; rg < 4; rg++){
                int rr = wv*32 + rt*16 + quad*4 + rg;
                int c  = ct*16 + lq;
                Ts[rr*LP + c] = (_Float16)(acc[rt][ct][rg] + c2s[c]);
            }
    stage_copy(w1aT1 + row*HID + half*64, lW);
    __syncthreads();

    zero_acc(acc);
    gemm_tile(Ts, Ws, acc, wv, lq, quad);       // out0 @ W1a1
    __syncthreads();

    stage_copy(Bh1 + (size_t)(node0 + row)*HID + half*64, Ts + row*LP + half*64);
    __syncthreads();

    #pragma unroll
    for (int rt = 0; rt < 2; rt++)
        #pragma unroll
        for (int ct = 0; ct < 8; ct++)
            #pragma unroll
            for (int rg = 0; rg < 4; rg++){
                int rr = wv*32 + rt*16 + quad*4 + rg;
                int c  = ct*16 + lq;
                float v = acc[rt][ct][rg] + (float)Ts[rr*LP + c] + b1s[c];
                Ah[(size_t)(node0 + rr)*HID + c] = (_Float16)v;
            }
}

// -------- final global nn: out = relu(agg@G1 + c1') @ G2 + c2 --------
__launch_bounds__(256, 2)
__global__ void k_gnn(const uint32_t* __restrict__ agg,
                      const _Float16* __restrict__ g1T, const _Float16* __restrict__ g2T,
                      const float* __restrict__ c1p, const float* __restrict__ gb2,
                      float* __restrict__ outf){
    __shared__ _Float16 Ts[128*LP];
    __shared__ _Float16 Ws[128*LP];
    __shared__ float c1s[128];
    __shared__ float c2s[128];
    const int tid = threadIdx.x;
    const int node0 = blockIdx.x * 128;
    if (tid < 128){ c1s[tid] = c1p[tid]; c2s[tid] = gb2[tid]; }
    const int row = tid >> 1, half = tid & 1;
    _Float16* lW = Ws + row*LP + half*64;

    {   // decode agg tile + stage G1^T
        const uint4* ga = (const uint4*)(agg + (size_t)(node0 + row)*HID + half*64);
        _Float16* lt = Ts + row*LP + half*64;
        #pragma unroll
        for (int j = 0; j < 16; j++){
            uint4 u = ga[j];
            uint2 o; o.x = pkh(decf(u.x), decf(u.y)); o.y = pkh(decf(u.z), decf(u.w));
            *(uint2*)(lt + j*4) = o;
        }
        stage_copy(g1T + row*HID + half*64, lW);
    }
    __syncthreads();

    const int wv = tid >> 6, lane = tid & 63, lq = lane & 15, quad = lane >> 4;
    f32x4 acc[2][8];
    zero_acc(acc);
    gemm_tile(Ts, Ws, acc, wv, lq, quad);
    __syncthreads();

    #pragma unroll
    for (int rt = 0; rt < 2; rt++)
        #pragma unroll
        for (int ct = 0; ct < 8; ct++)
            #pragma unroll
            for (int rg = 0; rg < 4; rg++){
                int rr = wv*32 + rt*16 + quad*4 + rg;
                int c  = ct*16 + lq;
                Ts[rr*LP + c] = (_Float16)fmaxf(acc[rt][ct][rg] + c1s[c], 0.f);
            }
    stage_copy(g2T + row*HID + half*64, lW);
    __syncthreads();

    zero_acc(acc);
    gemm_tile(Ts, Ws, acc, wv, lq, quad);

    #pragma unroll
    for (int rt = 0; rt < 2; rt++)
        #pragma unroll
        for (int ct = 0; ct < 8; ct++)
            #pragma unroll
            for (int rg = 0; rg < 4; rg++){
                int r = node0 + wv*32 + rt*16 + quad*4 + rg;
                int c = ct*16 + lq;
                outf[(size_t)r*HID + c] = acc[rt][ct][rg] + c2s[c];
            }
}

extern "C" void kernel_launch(void* const* d_in, const int* in_sizes, int n_in,
                              void* d_out, int out_size, void* d_ws, size_t ws_size,
                              hipStream_t stream){
    const float* x   = (const float*)d_in[0];
    const float* pos = (const float*)d_in[1];
    const int*   ei  = (const int*)d_in[2];
    const float* W[16];
    for (int i = 0; i < 16; i++) W[i] = (const float*)d_in[3 + i];
    // per layer l: lw1=W[8l+0] lb1=+1 lw2=+2 lb2=+3 gw1=+4 gb1=+5 gw2=+6 gb2=+7

    uint8_t* p = (uint8_t*)d_ws;
    _Float16* wT[10];
    for (int i = 0; i < 10; i++) wT[i] = (_Float16*)(p + (size_t)i * 32768);
    size_t off = 10 * 32768;
    _Float16* Ah  = (_Float16*)(p + off); off += (size_t)NN * HID * 2;
    _Float16* Bh0 = (_Float16*)(p + off); off += (size_t)NN * HID * 2;
    _Float16* Bh1 = (_Float16*)(p + off); off += (size_t)NN * HID * 2;
    uint32_t* agg = (uint32_t*)(p + off); off += (size_t)NN * HID * 4;
    uint32_t* cnt = (uint32_t*)(p + off); off += (size_t)NN * 4;
    uint32_t* cur = (uint32_t*)(p + off); off += (size_t)NN * 4;
    uint32_t* bsum = (uint32_t*)(p + off); off += 256 * 4;
    uint32_t* bofs = (uint32_t*)(p + off); off += 256 * 4;
    float* c1p = (float*)(p + off); off += 256 * 4;
    uint2* sedge = (uint2*)(p + off); off += (size_t)E2 * 8;
    (void)ws_size; (void)in_sizes; (void)n_in; (void)out_size;

    // weight transpose slots per layer: W1a^T, W1b^T, W2^T, G1^T, G2^T
    WT wt;
    for (int l = 0; l < 2; l++){
        wt.s[5*l + 0] = W[8*l + 0];
        wt.s[5*l + 1] = W[8*l + 0] + 128*128;
        wt.s[5*l + 2] = W[8*l + 2];
        wt.s[5*l + 3] = W[8*l + 4];
        wt.s[5*l + 4] = W[8*l + 6];
        for (int j = 0; j < 5; j++) wt.d[5*l + j] = wT[5*l + j];
    }
    k_prep<<<898, 256, 0, stream>>>(wt, cnt, W[3], W[4], W[5], W[11], W[12], W[13], c1p);

    // dst-sorted edge list (shared by both layers)
    k_hist<<<NE/256, 256, 0, stream>>>(ei, cnt);
    k_scan1<<<256, 256, 0, stream>>>(cnt, bsum);
    k_scan2<<<1, 256, 0, stream>>>(bsum, bofs);
    k_scan3<<<256, 256, 0, stream>>>(cnt, bofs, cur);
    k_scatter<<<(E2 + 255)/256, 256, 0, stream>>>(ei, cur, sedge);

    k_ab3<<<NN/128, 256, 0, stream>>>(x, pos, wT[0], wT[1], wT[6], W[1],
                                      Ah, Bh0, Bh1, agg);
    k_edge<<<E2/128, 256, 0, stream>>>(sedge, Ah, Bh0, wT[2], agg);
    k_gnn_ab<<<NN/128, 256, 0, stream>>>(agg, wT[3], wT[4], c1p, W[7],
                                         wT[5], Bh1, W[9], Ah);
    k_edge<<<E2/128, 256, 0, stream>>>(sedge, Ah, Bh1, wT[7], agg);
    k_gnn<<<NN/128, 256, 0, stream>>>(agg, wT[8], wT[9], c1p + 128, W[15],
                                      (float*)d_out);
}

// Round 4
// 486.156 us; speedup vs baseline: 1.1457x; 1.1091x over previous
//
#include <hip/hip_runtime.h>
#include <hip/hip_bf16.h>
#include <stdint.h>

#define NN 65536
#define NE 1048576
#define E2 (NE + NN)      // edges + self loops = 1,114,112 = 8704*128
#define HID 128
#define LP 136            // padded LDS row pitch (fp16 elems) for k_ab3/k_gnn tiles
#define RMAX 13           // max runs in LDS run-table (overflow -> global atomics)
#define TP 129            // run-table stride in words
#define TABW 1680         // ceil(RMAX*TP/4)*4 words
#define ENC_NEG 0x007FFFFFu   // encf(-inf)

typedef _Float16 h8v __attribute__((ext_vector_type(8)));
typedef __fp16 fp16x2 __attribute__((ext_vector_type(2)));
typedef __attribute__((ext_vector_type(4))) float f32x4;

__device__ __forceinline__ uint32_t pkh(float a, float b){
    union { fp16x2 h; uint32_t u; } v;
    v.h = __builtin_amdgcn_cvt_pkrtz(a, b);
    return v.u;
}
// monotone float->uint encoding for unsigned atomicMax (branchless)
__device__ __forceinline__ uint32_t encf(float x){
    union { float f; uint32_t u; } v; v.f = x;
    return v.u ^ (uint32_t)(((int32_t)v.u >> 31) | 0x80000000);
}
__device__ __forceinline__ float decf(uint32_t u){
    union { uint32_t u; float f; } v;
    v.u = u ^ (uint32_t)(~((int32_t)u >> 31) | 0x80000000);
    return v.f;
}

// direct global->LDS DMA, 16B per lane (dest = wave-uniform base + lane*16)
__device__ __forceinline__ void gl_lds16(const _Float16* g, _Float16* l){
    __builtin_amdgcn_global_load_lds(
        (const __attribute__((address_space(1))) uint32_t*)g,
        (__attribute__((address_space(3))) uint32_t*)l, 16, 0, 0);
}

// ---- stage one 64-elem half-row into LDS (padded LP layout) ----
__device__ __forceinline__ void stage_copy(const _Float16* g, _Float16* l){
    const uint4* gs = (const uint4*)g; uint4* ls = (uint4*)l;
    #pragma unroll
    for (int j = 0; j < 8; j++) ls[j] = gs[j];
}
__device__ __forceinline__ void stage_cvt(const float* g, _Float16* l){
    const float4* gs = (const float4*)g; uint4* ls = (uint4*)l;
    #pragma unroll
    for (int j = 0; j < 8; j++){
        float4 f0 = gs[2*j], f1 = gs[2*j+1];
        uint4 o; o.x = pkh(f0.x, f0.y); o.y = pkh(f0.z, f0.w);
        o.z = pkh(f1.x, f1.y); o.w = pkh(f1.z, f1.w);
        ls[j] = o;
    }
}

// 128x128x128 fp16 GEMM from padded LDS tiles (k_ab3 / k_gnn_ab / k_gnn)
__device__ __forceinline__ void gemm_tile(const _Float16* Ts, const _Float16* Ws,
                                          f32x4 (&acc)[2][8], int wv, int lq, int quad){
    #pragma unroll
    for (int k0 = 0; k0 < 128; k0 += 32){
        h8v af[2], bfr[8];
        #pragma unroll
        for (int rt = 0; rt < 2; rt++)
            af[rt] = *(const h8v*)(Ts + (wv*32 + rt*16 + lq)*LP + k0 + quad*8);
        #pragma unroll
        for (int ct = 0; ct < 8; ct++)
            bfr[ct] = *(const h8v*)(Ws + (ct*16 + lq)*LP + k0 + quad*8);
        #pragma unroll
        for (int rt = 0; rt < 2; rt++)
            #pragma unroll
            for (int ct = 0; ct < 8; ct++)
                acc[rt][ct] = __builtin_amdgcn_mfma_f32_16x16x32_f16(
                                  af[rt], bfr[ct], acc[rt][ct], 0, 0, 0);
    }
}

__device__ __forceinline__ void zero_acc(f32x4 (&acc)[2][8]){
    #pragma unroll
    for (int a = 0; a < 2; a++)
        #pragma unroll
        for (int b = 0; b < 8; b++)
            acc[a][b] = (f32x4){0.f, 0.f, 0.f, 0.f};
}

// ---------------- prep: weight transposes + cnt init + folded bias ----------------
struct WT { const float* s[10]; _Float16* d[10]; };
__global__ void k_prep(WT w, uint32_t* cnt,
                       const float* lb2_0, const float* gw1_0, const float* gb1_0,
                       const float* lb2_1, const float* gw1_1, const float* gb1_1,
                       float* c1p){
    int b = blockIdx.x;
    if (b < 640){
        int m = b >> 6;
        int t = (b & 63) * 256 + threadIdx.x;
        int n = t >> 7, k = t & 127;
        w.d[m][n*128 + k] = (_Float16)w.s[m][k*128 + n];
    } else if (b < 896){
        cnt[(b - 640)*256 + threadIdx.x] = 1u;        // self-loop pre-counted
    } else {
        // c1'[l][j] = gb1[j] + sum_k lb2[k]*gw1[k][j]   (folds b2 out of k_edge)
        int l = b - 896;
        int j = threadIdx.x;
        if (j < 128){
            const float* lb2 = l ? lb2_1 : lb2_0;
            const float* gw1 = l ? gw1_1 : gw1_0;
            float s = (l ? gb1_1 : gb1_0)[j];
            for (int k = 0; k < 128; k++) s += lb2[k] * gw1[k*128 + j];
            c1p[l*128 + j] = s;
        }
    }
}
__global__ void k_hist(const int* __restrict__ ei, uint32_t* cnt){
    int e = blockIdx.x * 256 + threadIdx.x;
    if (e < NE) atomicAdd(&cnt[ei[NE + e]], 1u);
}
__global__ void k_scan1(const uint32_t* __restrict__ cnt, uint32_t* __restrict__ bsum){
    __shared__ uint32_t ps[256];
    int t = threadIdx.x;
    ps[t] = cnt[blockIdx.x*256 + t]; __syncthreads();
    for (int off = 128; off > 0; off >>= 1){
        if (t < off) ps[t] += ps[t + off];
        __syncthreads();
    }
    if (t == 0) bsum[blockIdx.x] = ps[0];
}
__global__ void k_scan2(const uint32_t* __restrict__ bsum, uint32_t* __restrict__ bofs){
    __shared__ uint32_t ps[256];
    int t = threadIdx.x;
    uint32_t v = bsum[t];
    ps[t] = v; __syncthreads();
    for (int off = 1; off < 256; off <<= 1){
        uint32_t u = (t >= off) ? ps[t - off] : 0u;
        __syncthreads();
        ps[t] += u;
        __syncthreads();
    }
    bofs[t] = ps[t] - v;
}
__global__ void k_scan3(const uint32_t* __restrict__ cnt, const uint32_t* __restrict__ bofs,
                        uint32_t* __restrict__ cur){
    __shared__ uint32_t ps[256];
    int t = threadIdx.x, i = blockIdx.x*256 + t;
    uint32_t v = cnt[i];
    ps[t] = v; __syncthreads();
    for (int off = 1; off < 256; off <<= 1){
        uint32_t u = (t >= off) ? ps[t - off] : 0u;
        __syncthreads();
        ps[t] += u;
        __syncthreads();
    }
    cur[i] = bofs[blockIdx.x] + ps[t] - v;
}
__global__ void k_scatter(const int* __restrict__ ei, uint32_t* cur,
                          uint2* __restrict__ sedge){
    int e = blockIdx.x * 256 + threadIdx.x;
    if (e >= E2) return;
    uint32_t s, d;
    if (e < NE){ s = (uint32_t)ei[e]; d = (uint32_t)ei[NE + e]; }
    else { s = d = (uint32_t)(e - NE); }
    uint32_t p = atomicAdd(&cur[d], 1u);
    sedge[p] = make_uint2(s, d);
}

// ---------------- k_ab3: B0 = pos@W1b0 ; B1 = pos@W1b1 ; A0 = x@W1a0 + B0 + b1_0 ----
// pos staged once for both B GEMMs; also inits agg rows to enc(-inf).
__launch_bounds__(256, 2)
__global__ void k_ab3(const float* __restrict__ x, const float* __restrict__ pos,
                      const _Float16* __restrict__ w1aT0, const _Float16* __restrict__ w1bT0,
                      const _Float16* __restrict__ w1bT1, const float* __restrict__ lb1_0,
                      _Float16* __restrict__ Ah, _Float16* __restrict__ Bh0,
                      _Float16* __restrict__ Bh1, uint32_t* __restrict__ agg){
    __shared__ _Float16 Ts[128*LP];
    __shared__ _Float16 Ws[128*LP];
    __shared__ float b1s[128];
    const int tid = threadIdx.x;
    const int node0 = blockIdx.x * 128;
    if (tid < 128) b1s[tid] = lb1_0[tid];

    {   // init agg for this node range
        uint4* ap = (uint4*)(agg + (size_t)node0 * HID);
        uint4 v = make_uint4(ENC_NEG, ENC_NEG, ENC_NEG, ENC_NEG);
        #pragma unroll
        for (int i = 0; i < 16; i++) ap[tid + i*256] = v;
    }

    const int row = tid >> 1, half = tid & 1;
    _Float16* lT = Ts + row*LP + half*64;
    _Float16* lW = Ws + row*LP + half*64;

    stage_cvt(pos + (size_t)(node0 + row)*HID + half*64, lT);
    stage_copy(w1bT0 + row*HID + half*64, lW);
    __syncthreads();

    const int wv = tid >> 6, lane = tid & 63, lq = lane & 15, quad = lane >> 4;
    f32x4 acc0[2][8], acc1[2][8];
    zero_acc(acc0);
    gemm_tile(Ts, Ws, acc0, wv, lq, quad);     // acc0 = pos @ W1b0
    __syncthreads();

    #pragma unroll
    for (int rt = 0; rt < 2; rt++)
        #pragma unroll
        for (int ct = 0; ct < 8; ct++)
            #pragma unroll
            for (int rg = 0; rg < 4; rg++){
                int r = node0 + wv*32 + rt*16 + quad*4 + rg;
                int c = ct*16 + lq;
                Bh0[(size_t)r*HID + c] = (_Float16)acc0[rt][ct][rg];
            }
    stage_copy(w1bT1 + row*HID + half*64, lW);  // Ts (pos) kept
    __syncthreads();

    zero_acc(acc1);
    gemm_tile(Ts, Ws, acc1, wv, lq, quad);     // acc1 = pos @ W1b1
    __syncthreads();

    #pragma unroll
    for (int rt = 0; rt < 2; rt++)
        #pragma unroll
        for (int ct = 0; ct < 8; ct++)
            #pragma unroll
            for (int rg = 0; rg < 4; rg++){
                int r = node0 + wv*32 + rt*16 + quad*4 + rg;
                int c = ct*16 + lq;
                Bh1[(size_t)r*HID + c] = (_Float16)acc1[rt][ct][rg];
            }
    stage_cvt(x + (size_t)(node0 + row)*HID + half*64, lT);
    stage_copy(w1aT0 + row*HID + half*64, lW);
    __syncthreads();

    gemm_tile(Ts, Ws, acc0, wv, lq, quad);     // acc0 += x @ W1a0

    #pragma unroll
    for (int rt = 0; rt < 2; rt++)
        #pragma unroll
        for (int ct = 0; ct < 8; ct++)
            #pragma unroll
            for (int rg = 0; rg < 4; rg++){
                int r = node0 + wv*32 + rt*16 + quad*4 + rg;
                int c = ct*16 + lq;
                Ah[(size_t)r*HID + c] = (_Float16)(acc0[rt][ct][rg] + b1s[c]);
            }
}

// -------- edge kernel: agg[dst] = max over edges of relu(A[src]-B[dst]) @ W2 --------
// R4: 2-barrier structure at FULL resources (4 blocks/CU):
//  - W2 staged via global_load_lds DMA (no staging VGPRs): linear LDS dest +
//    inverse-XOR-swizzled per-lane global source; read side unchanged (XOR is
//    an involution).
//  - RMAX 20->13: LDS 44032->~40448 <= 40960 (4 blocks/CU). runs/window ~= 8.5
//    +- 0.7 (renewal stats) -> 6-sigma margin; overflow path stays correct.
//  - d_prev via shfl (no extra loads); edge loads issued before DMA so counted
//    vmcnt lets gather-pointer math wait only on them.
//  - __launch_bounds__(256,4): 128 unified regs (64 V + 64 A) = 4 waves/SIMD.
__launch_bounds__(256, 4)
__global__ void k_edge(const uint2* __restrict__ sedge,
                       const _Float16* __restrict__ Ah, const _Float16* __restrict__ Bh,
                       const _Float16* __restrict__ w2T,
                       uint32_t* __restrict__ agg){
    __shared__ _Float16 Ws[128*128];                 // 32768 B, swizzled W2
    __shared__ __align__(16) uint32_t tab[TABW];     // 6720 B run-table (own region)
    __shared__ int ds_s[128];
    __shared__ unsigned long long masks_s[2];
    __shared__ int run_dst_s[RMAX];
    const int tid = threadIdx.x;
    const int bid = blockIdx.x;
    const int lb  = (bid & 7) * (E2/128/8) + (bid >> 3);   // XCD swizzle
    const int e0 = lb * 128;
    const int wv = tid >> 6, lane = tid & 63, lq = lane & 15, quad = lane >> 4;
    const int r0 = wv*32 + lq, r1 = r0 + 16;

    // ---- edge loads first (oldest in vmem FIFO -> cheap counted wait) ----
    const uint2 ea = sedge[e0 + r0];
    const uint2 eb = sedge[e0 + r1];
    int d_cur = 0;
    if (tid < 128) d_cur = (int)sedge[e0 + tid].y;

    // ---- W2 global->LDS DMA: linear dest, inverse-swizzled source ----
    #pragma unroll
    for (int rnd = 0; rnd < 8; rnd++){
        int g = rnd*256 + wv*64 + lane;              // 16B chunk id 0..2047
        int r = g >> 4, kc = g & 15;
        gl_lds16(w2T + r*HID + ((kc ^ (r & 15)) << 3),
                 Ws + rnd*2048 + wv*512);
    }

    // gathers: issue ASAP; drain at barrier1 under DMA + LDS bookkeeping
    const _Float16* a0p = Ah + (size_t)ea.x*HID + quad*8;
    const _Float16* a1p = Ah + (size_t)eb.x*HID + quad*8;
    const _Float16* b0p = Bh + (size_t)ea.y*HID + quad*8;
    const _Float16* b1p = Bh + (size_t)eb.y*HID + quad*8;
    h8v A0[4], A1[4], B0[4], B1[4];
    #pragma unroll
    for (int i = 0; i < 4; i++){
        A0[i] = *(const h8v*)(a0p + 32*i);
        A1[i] = *(const h8v*)(a1p + 32*i);
        B0[i] = *(const h8v*)(b0p + 32*i);
        B1[i] = *(const h8v*)(b1p + 32*i);
    }

    // boundary flags: d_prev via in-wave shuffles (no extra global loads).
    // lanes with (r1==63) hold sedge[e0+63] in eb -> shfl lane 15 serves tid 64.
    bool flag = false;
    if (tid < 128){
        ds_s[tid] = d_cur;
        int d_up  = __shfl_up(d_cur, 1);
        int d_b63 = __shfl((int)eb.y, 15);
        if (tid & 63) flag = (d_cur != d_up);
        else          flag = (tid == 0) ? true : (d_cur != d_b63);
        unsigned long long m = __ballot(flag);
        if ((tid & 63) == 0) masks_s[tid >> 6] = m;
    }
    {   // init run-table (TABW/4 = 420 uint4)
        uint4* t4 = (uint4*)tab;
        const uint4 vneg = make_uint4(ENC_NEG, ENC_NEG, ENC_NEG, ENC_NEG);
        #pragma unroll
        for (int i = 0; i < 2; i++){
            int idx = tid + i*256;
            if (idx < TABW/4) t4[idx] = vneg;
        }
    }
    __syncthreads();                            // barrier1: Ws/ds_s/masks/tab ready

    const unsigned long long m0 = masks_s[0], m1 = masks_s[1];
    const int c0 = __popcll(m0);
    const int nruns = c0 + __popcll(m1);

    // boundary threads record their run's dst (read post-barrier2 only)
    if (flag){
        int r;
        if (tid < 64) r = __popcll(m0 & ((2ull << tid) - 1)) - 1;
        else          r = c0 + __popcll(m1 & ((2ull << (tid-64)) - 1)) - 1;
        if (r < RMAX) run_dst_s[r] = d_cur;
    }

    f32x4 acc[2][8];
    zero_acc(acc);

    const h8v zero8 = (h8v)(_Float16)0;
    #pragma unroll
    for (int i = 0; i < 4; i++){
        h8v a0 = __builtin_elementwise_max(A0[i] - B0[i], zero8);
        h8v a1 = __builtin_elementwise_max(A1[i] - B1[i], zero8);
        const int kcb = i*4;
        #pragma unroll
        for (int ct = 0; ct < 8; ct++){
            h8v b = *(const h8v*)(Ws + (ct*16 + lq)*128 + (((kcb + quad) ^ lq) << 3));
            acc[0][ct] = __builtin_amdgcn_mfma_f32_16x16x32_f16(a0, b, acc[0][ct], 0, 0, 0);
            acc[1][ct] = __builtin_amdgcn_mfma_f32_16x16x32_f16(a1, b, acc[1][ct], 0, 0, 0);
        }
    }

    // flush acc -> run-table (tab does not alias Ws: no barrier needed)
    #pragma unroll
    for (int rt = 0; rt < 2; rt++){
        const int rb = wv*32 + rt*16 + quad*4;
        int rid[4];
        #pragma unroll
        for (int i = 0; i < 4; i++){
            int r = rb + i;
            if (r < 64) rid[i] = __popcll(m0 & ((2ull << r) - 1)) - 1;
            else        rid[i] = c0 + __popcll(m1 & ((2ull << (r-64)) - 1)) - 1;
        }
        const bool b01 = rid[1] != rid[0];
        const bool b12 = rid[2] != rid[1];
        const bool b23 = rid[3] != rid[2];
        #pragma unroll
        for (int ct = 0; ct < 8; ct++){
            const int c = ct*16 + lq;
            float v0 = acc[rt][ct][0], v1 = acc[rt][ct][1];
            float v2 = acc[rt][ct][2], v3 = acc[rt][ct][3];
            #define FLUSH(ID, R, V) do{ uint32_t ev = encf(V); \
                if (__builtin_expect((ID) < RMAX, 1)) atomicMax(&tab[(ID)*TP + c], ev); \
                else atomicMax(&agg[(size_t)ds_s[R]*HID + c], ev); }while(0)
            if (b01) FLUSH(rid[0], rb+0, v0); else v1 = fmaxf(v1, v0);
            if (b12) FLUSH(rid[1], rb+1, v1); else v2 = fmaxf(v2, v1);
            if (b23) FLUSH(rid[2], rb+2, v2); else v3 = fmaxf(v3, v2);
            FLUSH(rid[3], rb+3, v3);
            #undef FLUSH
        }
    }
    __syncthreads();                            // barrier2: table + run_dst complete

    {   // flush: boundary runs -> atomicMax; interior runs sole-writer -> plain store
        const int c = tid & 127;
        const int ntab = nruns < RMAX ? nruns : RMAX;
        for (int r = tid >> 7; r < ntab; r += 2){
            uint32_t v = tab[r*TP + c];
            uint32_t* dst = &agg[(size_t)run_dst_s[r]*HID + c];
            if (r == 0 || r == nruns-1 || nruns > RMAX) atomicMax(dst, v);
            else *dst = v;
        }
    }
}

// -------- fused layer-0 global nn + layer-1 A: out0 = relu((agg)@G1 + c1')@G2 + c2 ;
//          A1 = out0@W1a1 + B1 + b1_1 ; re-inits agg rows for layer 1 --------
__launch_bounds__(256, 2)
__global__ void k_gnn_ab(uint32_t* __restrict__ agg,
                         const _Float16* __restrict__ g1T, const _Float16* __restrict__ g2T,
                         const float* __restrict__ c1p, const float* __restrict__ gb2,
                         const _Float16* __restrict__ w1aT1, const _Float16* __restrict__ Bh1,
                         const float* __restrict__ lb1_1,
                         _Float16* __restrict__ Ah){
    __shared__ _Float16 Ts[128*LP];
    __shared__ _Float16 Ws[128*LP];
    __shared__ float c1s[128];
    __shared__ float c2s[128];
    __shared__ float b1s[128];
    const int tid = threadIdx.x;
    const int node0 = blockIdx.x * 128;
    if (tid < 128){ c1s[tid] = c1p[tid]; c2s[tid] = gb2[tid]; b1s[tid] = lb1_1[tid]; }
    const int row = tid >> 1, half = tid & 1;
    _Float16* lW = Ws + row*LP + half*64;

    {   // decode agg tile (+re-init to enc(-inf)) and stage G1^T
        uint4* ga = (uint4*)(agg + (size_t)(node0 + row)*HID + half*64);
        _Float16* lt = Ts + row*LP + half*64;
        const uint4 vneg = make_uint4(ENC_NEG, ENC_NEG, ENC_NEG, ENC_NEG);
        #pragma unroll
        for (int j = 0; j < 16; j++){
            uint4 u = ga[j];
            ga[j] = vneg;
            uint2 o; o.x = pkh(decf(u.x), decf(u.y)); o.y = pkh(decf(u.z), decf(u.w));
            *(uint2*)(lt + j*4) = o;
        }
        stage_copy(g1T + row*HID + half*64, lW);
    }
    __syncthreads();

    const int wv = tid >> 6, lane = tid & 63, lq = lane & 15, quad = lane >> 4;
    f32x4 acc[2][8];
    zero_acc(acc);
    gemm_tile(Ts, Ws, acc, wv, lq, quad);       // agg @ G1
    __syncthreads();

    #pragma unroll
    for (int rt = 0; rt < 2; rt++)
        #pragma unroll
        for (int ct = 0; ct < 8; ct++)
            #pragma unroll
            for (int rg = 0; rg < 4; rg++){
                int rr = wv*32 + rt*16 + quad*4 + rg;
                int c  = ct*16 + lq;
                Ts[rr*LP + c] = (_Float16)fmaxf(acc[rt][ct][rg] + c1s[c], 0.f);
            }
    stage_copy(g2T + row*HID + half*64, lW);
    __syncthreads();

    zero_acc(acc);
    gemm_tile(Ts, Ws, acc, wv, lq, quad);       // P @ G2
    __syncthreads();

    #pragma unroll
    for (int rt = 0; rt < 2; rt++)              // out0 -> Ts (fp16), stage W1a1^T
        #pragma unroll
        for (int ct = 0; ct < 8; ct++)
            #pragma unroll
            for (int rg = 0; rg < 4; rg++){
                int rr = wv*32 + rt*16 + quad*4 + rg;
                int c  = ct*16 + lq;
                Ts[rr*LP + c] = (_Float16)(acc[rt][ct][rg] + c2s[c]);
            }
    stage_copy(w1aT1 + row*HID + half*64, lW);
    __syncthreads();

    zero_acc(acc);
    gemm_tile(Ts, Ws, acc, wv, lq, quad);       // out0 @ W1a1
    __syncthreads();

    stage_copy(Bh1 + (size_t)(node0 + row)*HID + half*64, Ts + row*LP + half*64);
    __syncthreads();

    #pragma unroll
    for (int rt = 0; rt < 2; rt++)
        #pragma unroll
        for (int ct = 0; ct < 8; ct++)
            #pragma unroll
            for (int rg = 0; rg < 4; rg++){
                int rr = wv*32 + rt*16 + quad*4 + rg;
                int c  = ct*16 + lq;
                float v = acc[rt][ct][rg] + (float)Ts[rr*LP + c] + b1s[c];
                Ah[(size_t)(node0 + rr)*HID + c] = (_Float16)v;
            }
}

// -------- final global nn: out = relu(agg@G1 + c1') @ G2 + c2 --------
__launch_bounds__(256, 2)
__global__ void k_gnn(const uint32_t* __restrict__ agg,
                      const _Float16* __restrict__ g1T, const _Float16* __restrict__ g2T,
                      const float* __restrict__ c1p, const float* __restrict__ gb2,
                      float* __restrict__ outf){
    __shared__ _Float16 Ts[128*LP];
    __shared__ _Float16 Ws[128*LP];
    __shared__ float c1s[128];
    __shared__ float c2s[128];
    const int tid = threadIdx.x;
    const int node0 = blockIdx.x * 128;
    if (tid < 128){ c1s[tid] = c1p[tid]; c2s[tid] = gb2[tid]; }
    const int row = tid >> 1, half = tid & 1;
    _Float16* lW = Ws + row*LP + half*64;

    {   // decode agg tile + stage G1^T
        const uint4* ga = (const uint4*)(agg + (size_t)(node0 + row)*HID + half*64);
        _Float16* lt = Ts + row*LP + half*64;
        #pragma unroll
        for (int j = 0; j < 16; j++){
            uint4 u = ga[j];
            uint2 o; o.x = pkh(decf(u.x), decf(u.y)); o.y = pkh(decf(u.z), decf(u.w));
            *(uint2*)(lt + j*4) = o;
        }
        stage_copy(g1T + row*HID + half*64, lW);
    }
    __syncthreads();

    const int wv = tid >> 6, lane = tid & 63, lq = lane & 15, quad = lane >> 4;
    f32x4 acc[2][8];
    zero_acc(acc);
    gemm_tile(Ts, Ws, acc, wv, lq, quad);
    __syncthreads();

    #pragma unroll
    for (int rt = 0; rt < 2; rt++)
        #pragma unroll
        for (int ct = 0; ct < 8; ct++)
            #pragma unroll
            for (int rg = 0; rg < 4; rg++){
                int rr = wv*32 + rt*16 + quad*4 + rg;
                int c  = ct*16 + lq;
                Ts[rr*LP + c] = (_Float16)fmaxf(acc[rt][ct][rg] + c1s[c], 0.f);
            }
    stage_copy(g2T + row*HID + half*64, lW);
    __syncthreads();

    zero_acc(acc);
    gemm_tile(Ts, Ws, acc, wv, lq, quad);

    #pragma unroll
    for (int rt = 0; rt < 2; rt++)
        #pragma unroll
        for (int ct = 0; ct < 8; ct++)
            #pragma unroll
            for (int rg = 0; rg < 4; rg++){
                int r = node0 + wv*32 + rt*16 + quad*4 + rg;
                int c = ct*16 + lq;
                outf[(size_t)r*HID + c] = acc[rt][ct][rg] + c2s[c];
            }
}

extern "C" void kernel_launch(void* const* d_in, const int* in_sizes, int n_in,
                              void* d_out, int out_size, void* d_ws, size_t ws_size,
                              hipStream_t stream){
    const float* x   = (const float*)d_in[0];
    const float* pos = (const float*)d_in[1];
    const int*   ei  = (const int*)d_in[2];
    const float* W[16];
    for (int i = 0; i < 16; i++) W[i] = (const float*)d_in[3 + i];
    // per layer l: lw1=W[8l+0] lb1=+1 lw2=+2 lb2=+3 gw1=+4 gb1=+5 gw2=+6 gb2=+7

    uint8_t* p = (uint8_t*)d_ws;
    _Float16* wT[10];
    for (int i = 0; i < 10; i++) wT[i] = (_Float16*)(p + (size_t)i * 32768);
    size_t off = 10 * 32768;
    _Float16* Ah  = (_Float16*)(p + off); off += (size_t)NN * HID * 2;
    _Float16* Bh0 = (_Float16*)(p + off); off += (size_t)NN * HID * 2;
    _Float16* Bh1 = (_Float16*)(p + off); off += (size_t)NN * HID * 2;
    uint32_t* agg = (uint32_t*)(p + off); off += (size_t)NN * HID * 4;
    uint32_t* cnt = (uint32_t*)(p + off); off += (size_t)NN * 4;
    uint32_t* cur = (uint32_t*)(p + off); off += (size_t)NN * 4;
    uint32_t* bsum = (uint32_t*)(p + off); off += 256 * 4;
    uint32_t* bofs = (uint32_t*)(p + off); off += 256 * 4;
    float* c1p = (float*)(p + off); off += 256 * 4;
    uint2* sedge = (uint2*)(p + off); off += (size_t)E2 * 8;
    (void)ws_size; (void)in_sizes; (void)n_in; (void)out_size;

    // weight transpose slots per layer: W1a^T, W1b^T, W2^T, G1^T, G2^T
    WT wt;
    for (int l = 0; l < 2; l++){
        wt.s[5*l + 0] = W[8*l + 0];
        wt.s[5*l + 1] = W[8*l + 0] + 128*128;
        wt.s[5*l + 2] = W[8*l + 2];
        wt.s[5*l + 3] = W[8*l + 4];
        wt.s[5*l + 4] = W[8*l + 6];
        for (int j = 0; j < 5; j++) wt.d[5*l + j] = wT[5*l + j];
    }
    k_prep<<<898, 256, 0, stream>>>(wt, cnt, W[3], W[4], W[5], W[11], W[12], W[13], c1p);

    // dst-sorted edge list (shared by both layers)
    k_hist<<<NE/256, 256, 0, stream>>>(ei, cnt);
    k_scan1<<<256, 256, 0, stream>>>(cnt, bsum);
    k_scan2<<<1, 256, 0, stream>>>(bsum, bofs);
    k_scan3<<<256, 256, 0, stream>>>(cnt, bofs, cur);
    k_scatter<<<(E2 + 255)/256, 256, 0, stream>>>(ei, cur, sedge);

    k_ab3<<<NN/128, 256, 0, stream>>>(x, pos, wT[0], wT[1], wT[6], W[1],
                                      Ah, Bh0, Bh1, agg);
    k_edge<<<E2/128, 256, 0, stream>>>(sedge, Ah, Bh0, wT[2], agg);
    k_gnn_ab<<<NN/128, 256, 0, stream>>>(agg, wT[3], wT[4], c1p, W[7],
                                         wT[5], Bh1, W[9], Ah);
    k_edge<<<E2/128, 256, 0, stream>>>(sedge, Ah, Bh1, wT[7], agg);
    k_gnn<<<NN/128, 256, 0, stream>>>(agg, wT[8], wT[9], c1p + 128, W[15],
                                      (float*)d_out);
}